// Round 8
// baseline (386.437 us; speedup 1.0000x reference)
//
#include <hip/hip_runtime.h>
#include <hip/hip_cooperative_groups.h>
#include <math.h>

namespace cg = cooperative_groups;

#define NN 511
#define HH 256
#define BB 4
#define CINC 4
#define COUTC 8
#define CROP 127
#define INV_NN2 (1.0f / ((float)NN * (float)NN))

typedef _Float16 f16;
typedef _Float16 f16x2 __attribute__((ext_vector_type(2)));
typedef _Float16 f16x8 __attribute__((ext_vector_type(8)));
typedef float    f32x4 __attribute__((ext_vector_type(4)));

// 32-bit twiddle: all products < 2^31.  forward twiddle = c - i*s
__device__ __forceinline__ void twid(int a, int b, float& c, float& s) {
    int m = (a * b) % NN;
    float phi = (float)(2.0 * M_PI / (double)NN) * (float)m;
    __sincosf(phi, &s, &c);
}

#define GLB_PTR(p) ((const __attribute__((address_space(1))) unsigned int*)(p))
#define LDS_PTR(p) ((__attribute__((address_space(3))) unsigned int*)(p))
__device__ __forceinline__ void gld16(const f16* g, f16* l) {
    __builtin_amdgcn_global_load_lds(GLB_PTR(g), LDS_PTR(l), 16, 0, 0);
}

#define LSTR 68   // epilogue LDS row stride (f16)

// ---------------------------------------------------------------------------
// GEMM tile: 128x64 block tile, 4 waves (2x2) x 64x32, BK=64, double-buffered
// LDS with single barrier per K-iter (prefetch issued after barrier overlaps
// the 16 MFMAs; next barrier's vmcnt(0) drains it). XOR-swizzled k-chunks on
// the fetch side; LDS stays lane-contiguous (global_load_lds requirement).
// A [M,K], Bt [N,K] row-major. Kt must be even (all stages: 4/8/16/8).
// ---------------------------------------------------------------------------
template<int EPI>
__device__ __forceinline__ void gemm_tile(
    const f16* __restrict__ A, const f16* __restrict__ Bt,
    f16* __restrict__ Ch, float* __restrict__ Cf,
    const float* __restrict__ bias, const float2* __restrict__ Wp,
    int Kt, int ldA, int ldB, int m0, int n0, int z,
    f16* As0, f16* As1, f16* Bs0, f16* Bs1)
{
    const int t    = threadIdx.x;
    const int row  = t >> 3;
    const int slot = t & 7;
    const int kg   = (slot ^ (row & 7)) << 3;
    const f16* Ap = A  + (size_t)(m0 + row) * ldA + kg;
    const f16* Bp = Bt + (size_t)(n0 + row) * ldB + kg;
    const int o8 = t * 8;

    const int lane = t & 63, w = t >> 6;
    const int wm = (w >> 1) * 64, wn = (w & 1) * 32;
    const int col = lane & 15, quad = lane >> 4;
    const int aswz = col & 7;
    const int offK0 = ((quad)     ^ aswz) << 3;
    const int offK1 = ((4 + quad) ^ aswz) << 3;

    f32x4 acc[4][2] = {};

    auto stage = [&](f16* Ad, f16* Bd_) {
        gld16(Ap,             Ad + o8);
        gld16(Ap +  32 * ldA, Ad + o8 + 2048);
        gld16(Ap +  64 * ldA, Ad + o8 + 4096);
        gld16(Ap +  96 * ldA, Ad + o8 + 6144);
        gld16(Bp,             Bd_ + o8);
        gld16(Bp +  32 * ldB, Bd_ + o8 + 2048);
        Ap += 64; Bp += 64;
    };
    auto compute = [&](const f16* Asrc, const f16* Bsrc) {
        const f16* a_col = Asrc + (wm + col) * 64;
        const f16* b_col = Bsrc + (wn + col) * 64;
        f16x8 af[4][2], bf[2][2];
        #pragma unroll
        for (int i = 0; i < 4; ++i) {
            af[i][0] = *(const f16x8*)(a_col + i * 16 * 64 + offK0);
            af[i][1] = *(const f16x8*)(a_col + i * 16 * 64 + offK1);
        }
        #pragma unroll
        for (int j = 0; j < 2; ++j) {
            bf[j][0] = *(const f16x8*)(b_col + j * 16 * 64 + offK0);
            bf[j][1] = *(const f16x8*)(b_col + j * 16 * 64 + offK1);
        }
        #pragma unroll
        for (int kk = 0; kk < 2; ++kk)
            #pragma unroll
            for (int i = 0; i < 4; ++i)
                #pragma unroll
                for (int j = 0; j < 2; ++j)
                    acc[i][j] = __builtin_amdgcn_mfma_f32_16x16x32_f16(
                        af[i][kk], bf[j][kk], acc[i][j], 0, 0, 0);
    };

    stage(As0, Bs0);                      // prologue: tile 0 -> buf0
    for (int kb = 0; kb < Kt; kb += 2) {
        __syncthreads();                  // buf0 staged; prior buf1 reads done
        stage(As1, Bs1);                  // prefetch tile kb+1 (Kt even)
        compute(As0, Bs0);                // overlaps with prefetch
        __syncthreads();                  // buf1 staged; buf0 reads done
        if (kb + 2 < Kt) stage(As0, Bs0); // prefetch tile kb+2
        compute(As1, Bs1);
    }

    if constexpr (EPI == 1) {
        // ---- fused Hermitian channel mix (stage B) ----
        f16* Ls = As0;                    // overlay: 128*68*2 = 17.4 KB < 32 KB
        __syncthreads();
        #pragma unroll
        for (int i = 0; i < 4; ++i)
        #pragma unroll
        for (int j = 0; j < 2; ++j) {
            const int ml = wm + i * 16 + quad * 4;
            const int nl = wn + j * 16 + col;
            #pragma unroll
            for (int r = 0; r < 4; ++r)
                Ls[(ml + r) * LSTR + nl] = (f16)acc[i][j][r];
        }
        __syncthreads();
        const int du = t >> 5, dv = t & 31;
        const int u = (m0 >> 4) + du;
        const int v = (n0 >> 1) + dv;
        const int u2 = (u == 0) ? 0 : NN - u;
        const int v2 = (v == 0) ? 0 : NN - v;
        const float gu = (u == 0) ? INV_NN2 : 2.f * INV_NN2;  // iFFT scale fold
        float fr[16], fi[16];
        #pragma unroll
        for (int bc = 0; bc < 16; ++bc) {
            f16x2 p = *(const f16x2*)&Ls[(du * 16 + bc) * LSTR + dv * 2];
            fr[bc] = (float)p.x;
            fi[bc] = (float)p.y;
        }
        #pragma unroll
        for (int o = 0; o < COUTC; ++o) {
            float whr[CINC], whi[CINC];
            #pragma unroll
            for (int c = 0; c < CINC; ++c) {
                size_t base = (size_t)(o * CINC + c) * NN;
                float2 w1 = Wp[(base + u)  * NN + v];
                float2 w2 = Wp[(base + u2) * NN + v2];
                whr[c] = 0.5f * (w1.x + w2.x);
                whi[c] = 0.5f * (w1.y - w2.y);
            }
            #pragma unroll
            for (int b = 0; b < BB; ++b) {
                float hr = 0.f, hi = 0.f;
                #pragma unroll
                for (int c = 0; c < CINC; ++c) {
                    hr += fr[b * 4 + c] * whr[c] - fi[b * 4 + c] * whi[c];
                    hi += fr[b * 4 + c] * whi[c] + fi[b * 4 + c] * whr[c];
                }
                f16x2 outp; outp.x = (f16)(hr * gu); outp.y = (f16)(hi * gu);
                *(f16x2*)&Ch[((size_t)((b * COUTC + o) * 256 + u)) * 1024 + v * 2] = outp;
            }
        }
        __syncthreads();   // Ls overlay dead before next phase reuses LDS
    } else {
        #pragma unroll
        for (int i = 0; i < 4; ++i)
        #pragma unroll
        for (int j = 0; j < 2; ++j) {
            const int mbase = m0 + wm + i * 16 + quad * 4;
            const int ncol  = n0 + wn + j * 16 + col;
            #pragma unroll
            for (int r = 0; r < 4; ++r) {
                const int mm = mbase + r;
                const float val = acc[i][j][r];
                if constexpr (EPI == 0) {          // stage A -> T1 rows u*16+z
                    int u = mm & 255;
                    int slotc = (mm < 256) ? ncol : 256 + ncol;
                    Ch[((size_t)(u * 16 + z)) * 512 + slotc] = (f16)val;
                } else if constexpr (EPI == 2) {   // stage D -> T2t (scale folded upstream)
                    int bo = mm >> 8, u = mm & 255;
                    int x     = (ncol < 256) ? ncol : ncol - 256;
                    int slotc = (ncol < 256) ? u : 256 + u;
                    Ch[((size_t)((bo << 8) + x)) * 512 + slotc] = (f16)val;
                } else {                            // stage E -> out fp32
                    int bo = ncol >> 8, x = ncol & 255;
                    Cf[((size_t)bo * 256 + mm) * 256 + x] = val + bias[bo & 7];
                }
            }
        }
    }
}

// ---------------------------------------------------------------------------
// ONE cooperative kernel: prep -> A -> B+mix -> D -> E with grid.sync().
// 512 blocks x 256 threads, 2 blocks/CU (48 KB LDS, launch_bounds(256,2)).
// ---------------------------------------------------------------------------
__global__ __launch_bounds__(256, 2)
void fourier_all(const float* __restrict__ im, const float2* __restrict__ W,
                 const float* __restrict__ bias, float* __restrict__ out,
                 f16* __restrict__ Aa, f16* __restrict__ Bb,
                 f16* __restrict__ Bd, f16* __restrict__ Ae,
                 f16* __restrict__ imT, f16* __restrict__ T1,
                 f16* __restrict__ feats, f16* __restrict__ T2t)
{
    cg::grid_group grid = cg::this_grid();
    __shared__ __align__(16) char smem[49152];
    f16* As0 = (f16*)smem;                    // 16 KB
    f16* As1 = (f16*)(smem + 16384);          // 16 KB
    f16* Bs0 = (f16*)(smem + 32768);          // 8 KB
    f16* Bs1 = (f16*)(smem + 40960);          // 8 KB

    const int bid = blockIdx.x;

    // ---- phase 0: prep (grid-stride over 2,359,296 elements) ----
    for (int idx = bid * 256 + (int)threadIdx.x; idx < 2359296; idx += 131072) {
        if (idx < 131072) {                       // Aa_h [512 x 256]
            int m = idx >> 8, y = idx & 255;
            float c, s;
            if (m < 256) { twid(m, y, c, s);       Aa[idx] = (f16)c;    }
            else         { twid(m - 256, y, c, s); Aa[idx] = (f16)(-s); }
        } else if (idx < 655360) {                // Bb_t [1024 x 512], n = 2v+ri
            int i = idx - 131072;
            int n = i >> 9, k = i & 511;
            int v = n >> 1, ri = n & 1;
            float val = 0.f;
            if (v < NN) {
                int x = k & 255;
                float c, s; twid(v, x, c, s);
                if (ri == 0) val = (k < 256) ? c  : s;
                else         val = (k < 256) ? -s : c;
            }
            Bb[i] = (f16)val;
        } else if (idx < 1179648) {               // Bd_t [512 x 1024], k = 2v+ri
            int i = idx - 655360;
            int n = i >> 10, k = i & 1023;
            int v = k >> 1, ri = k & 1;
            float val = 0.f;
            if (v < NN) {
                int x = n & 255;
                float c, s; twid(v, x + CROP, c, s);
                if (ri == 0) val = (n < 256) ? c  : s;
                else         val = (n < 256) ? -s : c;
            }
            Bd[i] = (f16)val;
        } else if (idx < 1310720) {               // Ae_h [256 x 512]
            int i = idx - 1179648;
            int y = i >> 9, k = i & 511;
            float c, s;
            if (k < 256) { twid(k, y + CROP, c, s);       Ae[i] = (f16)c;    }
            else         { twid(k - 256, y + CROP, c, s); Ae[i] = (f16)(-s); }
        } else {                                  // imT transpose
            int i = idx - 1310720;
            int bc = i >> 16, r = i & 65535;
            int y = r >> 8, x = r & 255;
            imT[(size_t)bc * 65536 + x * 256 + y] = (f16)im[i];
        }
    }
    grid.sync();

    // ---- phase A: 256 tiles: per bc [512 x 256] = Aa_h x imT[bc] -> T1 ----
    if (bid < 256) {
        int m0 = (bid & 3) * 128, n0 = ((bid >> 2) & 3) * 64, z = bid >> 4;
        gemm_tile<0>(Aa, imT + (size_t)z * 65536, T1, nullptr, nullptr, nullptr,
                     4, 256, 256, m0, n0, z, As0, As1, Bs0, Bs1);
    }
    grid.sync();

    // ---- phase B: 512 tiles: [4096 x 1024] GEMM + Hermitian mix -> feats ----
    {
        int m0 = (bid & 31) * 128, n0 = (bid >> 5) * 64;
        gemm_tile<1>(T1, Bb, feats, nullptr, nullptr, W,
                     8, 512, 512, m0, n0, 0, As0, As1, Bs0, Bs1);
    }
    grid.sync();

    // ---- phase D: 512 tiles: [8192 x 512] = feats x Bd -> T2t ----
    {
        int m0 = (bid & 63) * 128, n0 = (bid >> 6) * 64;
        gemm_tile<2>(feats, Bd, T2t, nullptr, nullptr, nullptr,
                     16, 1024, 1024, m0, n0, 0, As0, As1, Bs0, Bs1);
    }
    grid.sync();

    // ---- phase E: 256 tiles: [256 x 8192] = Ae_h x T2t + bias -> out ----
    if (bid < 256) {
        int m0 = (bid & 1) * 128, n0 = (bid >> 1) * 64;
        gemm_tile<3>(Ae, T2t, nullptr, out, bias, nullptr,
                     8, 512, 512, m0, n0, 0, As0, As1, Bs0, Bs1);
    }
}

// ---------------------------------------------------------------------------
// kernel_launch
// ---------------------------------------------------------------------------
extern "C" void kernel_launch(void* const* d_in, const int* in_sizes, int n_in,
                              void* d_out, int out_size, void* d_ws, size_t ws_size,
                              hipStream_t stream) {
    const float*  im   = (const float*)d_in[0];
    const float2* W    = (const float2*)d_in[1];
    const float*  bias = (const float*)d_in[2];
    float*        out  = (float*)d_out;

    char* ws = (char*)d_ws;
    f16* Aa    = (f16*)(ws);                    // 512*256    = 256 KB
    f16* Bb    = (f16*)(ws + 262144);           // 1024*512   = 1 MB
    f16* Bd    = (f16*)(ws + 1310720);          // 512*1024   = 1 MB
    f16* Ae    = (f16*)(ws + 2359296);          // 256*512    = 256 KB
    f16* imT   = (f16*)(ws + 2621440);          // 16*256*256 = 2 MB
    f16* T1    = (f16*)(ws + 4718592);          // 4096*512   = 4 MB
    f16* feats = (f16*)(ws + 8912896);          // 8192*1024  = 16 MB
    f16* T2t   = (f16*)(ws + 25690112);         // 8192*512   = 8 MB (end 33.7 MB)

    void* args[] = {&im, &W, &bias, &out, &Aa, &Bb, &Bd, &Ae,
                    &imT, &T1, &feats, &T2t};
    hipLaunchCooperativeKernel((void*)fourier_all, dim3(512), dim3(256),
                               args, 0, stream);
}

// Round 9
// 150.331 us; speedup vs baseline: 2.5706x; 2.5706x over previous
//
#include <hip/hip_runtime.h>
#include <math.h>

#define NN 511
#define HH 256
#define BB 4
#define CINC 4
#define COUTC 8
#define CROP 127
#define INV_NN2 (1.0f / ((float)NN * (float)NN))

typedef _Float16 f16;
typedef _Float16 f16x2 __attribute__((ext_vector_type(2)));
typedef _Float16 f16x8 __attribute__((ext_vector_type(8)));
typedef float    f32x4 __attribute__((ext_vector_type(4)));

// 32-bit twiddle: all products < 2^31.  forward twiddle = c - i*s
__device__ __forceinline__ void twid(int a, int b, float& c, float& s) {
    int m = (a * b) % NN;
    float phi = (float)(2.0 * M_PI / (double)NN) * (float)m;
    __sincosf(phi, &s, &c);
}

// ---------------------------------------------------------------------------
// ONE fused prep kernel.  Element ranges:
//   Aa  [512 x 256]              :       0 .. 131072
//   Bb_t [1024 x 512] (n=2v+ri)  :  131072 .. 655360
//   Bd_t [512 x 1024] (k=2v+ri)  :  655360 .. 1179648
//   Ae  [256 x 512]              : 1179648 .. 1310720
//   imT [16][256x256] transpose  : 1310720 .. 2359296
// ---------------------------------------------------------------------------
__global__ void prep_all(const float* __restrict__ im,
                         f16* __restrict__ Aa, f16* __restrict__ Bb,
                         f16* __restrict__ Bd, f16* __restrict__ Ae,
                         f16* __restrict__ imT) {
    int idx = blockIdx.x * 256 + threadIdx.x;
    if (idx < 131072) {                       // Aa_h [512 x 256]
        int m = idx >> 8, y = idx & 255;
        float c, s;
        if (m < 256) { twid(m, y, c, s);       Aa[idx] = (f16)c;    }
        else         { twid(m - 256, y, c, s); Aa[idx] = (f16)(-s); }
    } else if (idx < 655360) {                // Bb_t [1024 x 512], n = 2v+ri
        int i = idx - 131072;
        int n = i >> 9, k = i & 511;
        int v = n >> 1, ri = n & 1;
        float val = 0.f;
        if (v < NN) {
            int x = k & 255;
            float c, s; twid(v, x, c, s);
            if (ri == 0) val = (k < 256) ? c  : s;   // Fr = sum T1r*c + T1i*s
            else         val = (k < 256) ? -s : c;   // Fi = sum -T1r*s + T1i*c
        }
        Bb[i] = (f16)val;
    } else if (idx < 1179648) {               // Bd_t [512 x 1024], k = 2v+ri
        int i = idx - 655360;
        int n = i >> 10, k = i & 1023;
        int v = k >> 1, ri = k & 1;
        float val = 0.f;
        if (v < NN) {
            int x = n & 255;
            float c, s; twid(v, x + CROP, c, s);
            if (ri == 0) val = (n < 256) ? c  : s;   // h_r coeff (T2r | T2i)
            else         val = (n < 256) ? -s : c;   // h_i coeff
        }
        Bd[i] = (f16)val;
    } else if (idx < 1310720) {               // Ae_h [256 x 512]
        int i = idx - 1179648;
        int y = i >> 9, k = i & 511;
        float c, s;
        if (k < 256) { twid(k, y + CROP, c, s);       Ae[i] = (f16)c;    }
        else         { twid(k - 256, y + CROP, c, s); Ae[i] = (f16)(-s); }
    } else if (idx < 2359296) {               // imT transpose
        int i = idx - 1310720;
        int bc = i >> 16, r = i & 65535;
        int y = r >> 8, x = r & 255;
        imT[(size_t)bc * 65536 + x * 256 + y] = (f16)im[i];
    }
}

// ---------------------------------------------------------------------------
// GEMM machinery: 128x64 block tile, 4 waves (2x2) x 64x32, BK=64,
// DOUBLE-BUFFERED LDS: prefetch of tile k+1 issued right after the barrier,
// overlapping the 16 MFMAs of tile k; the next barrier's vmcnt(0) drain then
// waits on loads that already ran under compute. One barrier per tile.
// XOR-swizzled k-chunks on the fetch side (LDS stays lane-contiguous,
// required by global_load_lds). A [M,K], Bt [N,K] row-major. Kt even.
// ---------------------------------------------------------------------------
#define GLB_PTR(p) ((const __attribute__((address_space(1))) unsigned int*)(p))
#define LDS_PTR(p) ((__attribute__((address_space(3))) unsigned int*)(p))
__device__ __forceinline__ void gld16(const f16* g, f16* l) {
    __builtin_amdgcn_global_load_lds(GLB_PTR(g), LDS_PTR(l), 16, 0, 0);
}

#define STAGE(Abuf, Bbuf)                         \
    do {                                          \
        gld16(Ap,            (Abuf) + o8);        \
        gld16(Ap + 32 * ldA, (Abuf) + o8 + 2048); \
        gld16(Ap + 64 * ldA, (Abuf) + o8 + 4096); \
        gld16(Ap + 96 * ldA, (Abuf) + o8 + 6144); \
        gld16(Bp,            (Bbuf) + o8);        \
        gld16(Bp + 32 * ldB, (Bbuf) + o8 + 2048); \
        Ap += 64; Bp += 64;                       \
    } while (0)

#define COMPUTE(Abuf, Bbuf)                                                   \
    do {                                                                      \
        const f16* a_col = (Abuf) + (wm + col) * 64;                          \
        const f16* b_col = (Bbuf) + (wn + col) * 64;                          \
        f16x8 af[4][2], bf[2][2];                                             \
        _Pragma("unroll")                                                     \
        for (int i = 0; i < 4; ++i) {                                         \
            af[i][0] = *(const f16x8*)(a_col + i * 16 * 64 + offK0);          \
            af[i][1] = *(const f16x8*)(a_col + i * 16 * 64 + offK1);          \
        }                                                                     \
        _Pragma("unroll")                                                     \
        for (int j = 0; j < 2; ++j) {                                         \
            bf[j][0] = *(const f16x8*)(b_col + j * 16 * 64 + offK0);          \
            bf[j][1] = *(const f16x8*)(b_col + j * 16 * 64 + offK1);          \
        }                                                                     \
        _Pragma("unroll")                                                     \
        for (int kk = 0; kk < 2; ++kk)                                        \
            _Pragma("unroll")                                                 \
            for (int i = 0; i < 4; ++i)                                       \
                _Pragma("unroll")                                             \
                for (int j = 0; j < 2; ++j)                                   \
                    acc[i][j] = __builtin_amdgcn_mfma_f32_16x16x32_f16(       \
                        af[i][kk], bf[j][kk], acc[i][j], 0, 0, 0);            \
    } while (0)

#define GEMM_PREAMBLE                                                         \
    const int t    = threadIdx.x;                                             \
    const int row  = t >> 3;                                                  \
    const int slot = t & 7;                                                   \
    const int kg   = (slot ^ (row & 7)) << 3;                                 \
    const f16* Ap = A  + (size_t)(m0 + row) * ldA + kg;                       \
    const f16* Bp = Bt + (size_t)(n0 + row) * ldB + kg;                       \
    const int o8 = t * 8;                                                     \
    const int lane = t & 63, w = t >> 6;                                      \
    const int wm = (w >> 1) * 64, wn = (w & 1) * 32;                          \
    const int col = lane & 15, quad = lane >> 4;                              \
    const int aswz = col & 7;                                                 \
    const int offK0 = ((quad)     ^ aswz) << 3;                               \
    const int offK1 = ((4 + quad) ^ aswz) << 3;                               \
    f32x4 acc[4][2] = {};                                                     \
    STAGE(As0, Bs0);                                                          \
    for (int kb = 0; kb < Kt; kb += 2) {                                      \
        __syncthreads();                                                      \
        STAGE(As1, Bs1);                                                      \
        COMPUTE(As0, Bs0);                                                    \
        __syncthreads();                                                      \
        if (kb + 2 < Kt) STAGE(As0, Bs0);                                     \
        COMPUTE(As1, Bs1);                                                    \
    }

// ---------------------------------------------------------------------------
// Generic GEMM for stages A, D, E.
// ---------------------------------------------------------------------------
template<int EPI>
__global__ __launch_bounds__(256)
void gemm128x64(const f16* __restrict__ A, const f16* __restrict__ Bt,
                f16* __restrict__ Ch, float* __restrict__ Cf,
                const float* __restrict__ bias,
                int Kt, int ldA, int ldB, size_t sA, size_t sB) {
    __shared__ __align__(16) f16 As0[128 * 64];   // 16 KB
    __shared__ __align__(16) f16 As1[128 * 64];   // 16 KB
    __shared__ __align__(16) f16 Bs0[64 * 64];    // 8 KB
    __shared__ __align__(16) f16 Bs1[64 * 64];    // 8 KB

    const int z  = blockIdx.z;
    const int m0 = blockIdx.x * 128;
    const int n0 = blockIdx.y * 64;
    A  += (size_t)z * sA;
    Bt += (size_t)z * sB;

    GEMM_PREAMBLE

    #pragma unroll
    for (int i = 0; i < 4; ++i)
    #pragma unroll
    for (int j = 0; j < 2; ++j) {
        const int mbase = m0 + wm + i * 16 + quad * 4;
        const int ncol  = n0 + wn + j * 16 + col;
        #pragma unroll
        for (int r = 0; r < 4; ++r) {
            const int mm = mbase + r;
            const float val = acc[i][j][r];
            if constexpr (EPI == 0) {          // stage A -> T1 rows u*16+bc
                int u = mm & 255;
                int slotc = (mm < 256) ? ncol : 256 + ncol;
                Ch[((size_t)(u * 16 + z)) * 512 + slotc] = (f16)val;
            } else if constexpr (EPI == 2) {   // stage D -> T2t [bo*256+x][512]
                int bo = mm >> 8, u = mm & 255;
                int x     = (ncol < 256) ? ncol : ncol - 256;
                int slotc = (ncol < 256) ? u : 256 + u;
                Ch[((size_t)((bo << 8) + x)) * 512 + slotc] = (f16)val;
            } else {                            // stage E -> out fp32
                int bo = ncol >> 8, x = ncol & 255;
                Cf[((size_t)bo * 256 + mm) * 256 + x] = val + bias[bo & 7];
            }
        }
    }
}

// ---------------------------------------------------------------------------
// Stage B + Hermitian channel mix fused (iFFT scale g_u/N^2 folded here).
// ---------------------------------------------------------------------------
#define LSTR 68   // epilogue LDS row stride (f16)
__global__ __launch_bounds__(256)
void gemmB_fused(const f16* __restrict__ A, const f16* __restrict__ Bt,
                 const float2* __restrict__ W, f16* __restrict__ feats) {
    __shared__ __align__(16) f16 As0[128 * 64];
    __shared__ __align__(16) f16 As1[128 * 64];
    __shared__ __align__(16) f16 Bs0[64 * 64];
    __shared__ __align__(16) f16 Bs1[64 * 64];

    const int m0 = blockIdx.x * 128;      // u0 = blockIdx.x*8
    const int n0 = blockIdx.y * 64;       // v0 = blockIdx.y*32
    const int Kt = 8, ldA = 512, ldB = 512;

    GEMM_PREAMBLE

    // acc -> LDS F tile (overlay on As0/As1: 128*68*2 = 17.4 KB < 32 KB)
    f16* Ls = As0;
    __syncthreads();
    #pragma unroll
    for (int i = 0; i < 4; ++i)
    #pragma unroll
    for (int j = 0; j < 2; ++j) {
        const int ml = wm + i * 16 + quad * 4;
        const int nl = wn + j * 16 + col;
        #pragma unroll
        for (int r = 0; r < 4; ++r)
            Ls[(ml + r) * LSTR + nl] = (f16)acc[i][j][r];
    }
    __syncthreads();

    // Hermitian channel mix: one thread per (u,v) in tile
    const int du = t >> 5, dv = t & 31;
    const int u = (m0 >> 4) + du;
    const int v = (n0 >> 1) + dv;
    const int u2 = (u == 0) ? 0 : NN - u;
    const int v2 = (v == 0) ? 0 : NN - v;
    const float gu = (u == 0) ? INV_NN2 : 2.f * INV_NN2;

    float fr[16], fi[16];
    #pragma unroll
    for (int bc = 0; bc < 16; ++bc) {
        f16x2 p = *(const f16x2*)&Ls[(du * 16 + bc) * LSTR + dv * 2];
        fr[bc] = (float)p.x;
        fi[bc] = (float)p.y;
    }

    #pragma unroll
    for (int o = 0; o < COUTC; ++o) {
        float whr[CINC], whi[CINC];
        #pragma unroll
        for (int c = 0; c < CINC; ++c) {
            size_t base = (size_t)(o * CINC + c) * NN;
            float2 w1 = W[(base + u)  * NN + v];
            float2 w2 = W[(base + u2) * NN + v2];
            whr[c] = 0.5f * (w1.x + w2.x);
            whi[c] = 0.5f * (w1.y - w2.y);
        }
        #pragma unroll
        for (int b = 0; b < BB; ++b) {
            float hr = 0.f, hi = 0.f;
            #pragma unroll
            for (int c = 0; c < CINC; ++c) {
                hr += fr[b * 4 + c] * whr[c] - fi[b * 4 + c] * whi[c];
                hi += fr[b * 4 + c] * whi[c] + fi[b * 4 + c] * whr[c];
            }
            f16x2 outp; outp.x = (f16)(hr * gu); outp.y = (f16)(hi * gu);
            *(f16x2*)&feats[((size_t)((b * COUTC + o) * 256 + u)) * 1024 + v * 2] = outp;
        }
    }
}

// ---------------------------------------------------------------------------
// kernel_launch
// ---------------------------------------------------------------------------
extern "C" void kernel_launch(void* const* d_in, const int* in_sizes, int n_in,
                              void* d_out, int out_size, void* d_ws, size_t ws_size,
                              hipStream_t stream) {
    const float*  im   = (const float*)d_in[0];
    const float2* W    = (const float2*)d_in[1];
    const float*  bias = (const float*)d_in[2];
    float*        out  = (float*)d_out;

    char* ws = (char*)d_ws;
    f16* Aa    = (f16*)(ws);                    // 512*256    = 256 KB
    f16* Bb    = (f16*)(ws + 262144);           // 1024*512   = 1 MB
    f16* Bd    = (f16*)(ws + 1310720);          // 512*1024   = 1 MB
    f16* Ae    = (f16*)(ws + 2359296);          // 256*512    = 256 KB
    f16* imT   = (f16*)(ws + 2621440);          // 16*256*256 = 2 MB
    f16* T1    = (f16*)(ws + 4718592);          // 4096*512   = 4 MB
    f16* feats = (f16*)(ws + 8912896);          // 8192*1024  = 16 MB
    f16* T2t   = (f16*)(ws + 25690112);         // 8192*512   = 8 MB (end 33.7 MB)

    // fused preps (2,359,296 elements)
    prep_all<<<9216, 256, 0, stream>>>(im, Aa, Bb, Bd, Ae, imT);

    // Stage A: per bc: [512 x 256] = Aa_h x imT[bc] -> T1 rows u*16+bc
    gemm128x64<0><<<dim3(4, 4, 16), 256, 0, stream>>>(Aa, imT, T1, nullptr, nullptr,
                                                      4, 256, 256, 0, 65536);
    // Stage B + mix: [4096 x 1024] GEMM -> in-LDS F -> Hermitian mix -> feats
    gemmB_fused<<<dim3(32, 16), 256, 0, stream>>>(T1, Bb, W, feats);

    // Stage D: [8192 x 512] = feats x Bd -> T2t (scale folded in feats)
    gemm128x64<2><<<dim3(64, 8, 1), 256, 0, stream>>>(feats, Bd, T2t, nullptr, nullptr,
                                                      16, 1024, 1024, 0, 0);
    // Stage E: [256 x 8192] = Ae_h x T2t + bias -> out
    gemm128x64<3><<<dim3(2, 128, 1), 256, 0, stream>>>(Ae, T2t, nullptr, out, bias,
                                                       8, 512, 512, 0, 0);
}

// Round 11
// 148.453 us; speedup vs baseline: 2.6031x; 1.0127x over previous
//
#include <hip/hip_runtime.h>
#include <math.h>

#define NN 511
#define HH 256
#define BB 4
#define CINC 4
#define COUTC 8
#define CROP 127
#define INV_NN2 (1.0f / ((float)NN * (float)NN))

typedef _Float16 f16;
typedef _Float16 f16x2 __attribute__((ext_vector_type(2)));
typedef _Float16 f16x8 __attribute__((ext_vector_type(8)));
typedef float    f32x16 __attribute__((ext_vector_type(16)));

// 32-bit twiddle: all products < 2^31.  forward twiddle = c - i*s
__device__ __forceinline__ void twid(int a, int b, float& c, float& s) {
    int m = (a * b) % NN;
    float phi = (float)(2.0 * M_PI / (double)NN) * (float)m;
    __sincosf(phi, &s, &c);
}

// ---------------------------------------------------------------------------
// ONE fused prep kernel.  Element ranges:
//   Aa  [512 x 256]              :       0 .. 131072
//   Bb_t [1024 x 512] (n=2v+ri)  :  131072 .. 655360
//   Bd_t [512 x 1024] (k=2v+ri)  :  655360 .. 1179648
//   Ae  [256 x 512]              : 1179648 .. 1310720
//   imT [16][256x256] transpose  : 1310720 .. 2359296  (write-coalesced)
// ---------------------------------------------------------------------------
__global__ void prep_all(const float* __restrict__ im,
                         f16* __restrict__ Aa, f16* __restrict__ Bb,
                         f16* __restrict__ Bd, f16* __restrict__ Ae,
                         f16* __restrict__ imT) {
    int idx = blockIdx.x * 256 + threadIdx.x;
    if (idx < 131072) {                       // Aa_h [512 x 256]
        int m = idx >> 8, y = idx & 255;
        float c, s;
        if (m < 256) { twid(m, y, c, s);       Aa[idx] = (f16)c;    }
        else         { twid(m - 256, y, c, s); Aa[idx] = (f16)(-s); }
    } else if (idx < 655360) {                // Bb_t [1024 x 512], n = 2v+ri
        int i = idx - 131072;
        int n = i >> 9, k = i & 511;
        int v = n >> 1, ri = n & 1;
        float val = 0.f;
        if (v < NN) {
            int x = k & 255;
            float c, s; twid(v, x, c, s);
            if (ri == 0) val = (k < 256) ? c  : s;   // Fr = sum T1r*c + T1i*s
            else         val = (k < 256) ? -s : c;   // Fi = sum -T1r*s + T1i*c
        }
        Bb[i] = (f16)val;
    } else if (idx < 1179648) {               // Bd_t [512 x 1024], k = 2v+ri
        int i = idx - 655360;
        int n = i >> 10, k = i & 1023;
        int v = k >> 1, ri = k & 1;
        float val = 0.f;
        if (v < NN) {
            int x = n & 255;
            float c, s; twid(v, x + CROP, c, s);
            if (ri == 0) val = (n < 256) ? c  : s;   // h_r coeff (T2r | T2i)
            else         val = (n < 256) ? -s : c;   // h_i coeff
        }
        Bd[i] = (f16)val;
    } else if (idx < 1310720) {               // Ae_h [256 x 512]
        int i = idx - 1179648;
        int y = i >> 9, k = i & 511;
        float c, s;
        if (k < 256) { twid(k, y + CROP, c, s);       Ae[i] = (f16)c;    }
        else         { twid(k - 256, y + CROP, c, s); Ae[i] = (f16)(-s); }
    } else if (idx < 2359296) {               // imT: write-coalesced transpose
        int i = idx - 1310720;
        int bc = i >> 16, r = i & 65535;
        int x = r >> 8, y = r & 255;          // y fastest -> dst linear
        imT[i] = (f16)im[(size_t)bc * 65536 + y * 256 + x];
    }
}

// ---------------------------------------------------------------------------
// GEMM machinery: 128x64 block tile, 4 waves (2x2) x 64x32 wave tile, BK=64,
// 32x32x16 MFMA core (2 m-blocks of 32x32 per wave; 8 MFMA / iter — higher
// peak rate + half the instruction count vs 16x16x32). Double-buffered LDS,
// one barrier per tile; XOR-swizzled k-chunks on the fetch side (LDS stays
// lane-contiguous per global_load_lds). A [M,K], Bt [N,K] row-major. Kt even.
// ---------------------------------------------------------------------------
#define GLB_PTR(p) ((const __attribute__((address_space(1))) unsigned int*)(p))
#define LDS_PTR(p) ((__attribute__((address_space(3))) unsigned int*)(p))
__device__ __forceinline__ void gld16(const f16* g, f16* l) {
    __builtin_amdgcn_global_load_lds(GLB_PTR(g), LDS_PTR(l), 16, 0, 0);
}

#define STAGE(Abuf, Bbuf)                         \
    do {                                          \
        gld16(Ap,            (Abuf) + o8);        \
        gld16(Ap + 32 * ldA, (Abuf) + o8 + 2048); \
        gld16(Ap + 64 * ldA, (Abuf) + o8 + 4096); \
        gld16(Ap + 96 * ldA, (Abuf) + o8 + 6144); \
        gld16(Bp,            (Bbuf) + o8);        \
        gld16(Bp + 32 * ldB, (Bbuf) + o8 + 2048); \
        Ap += 64; Bp += 64;                       \
    } while (0)

// 32x32x16 fragment: A[m=lane&31][k=(lane>>5)*8+j]; chunk = s*2 + (lane>>5),
// stored at slot chunk^(row&7) (row&7 == ln31&7 for all rows we touch).
#define COMPUTE(Abuf, Bbuf)                                                   \
    do {                                                                      \
        _Pragma("unroll")                                                     \
        for (int s = 0; s < 4; ++s) {                                         \
            const int off = (((s << 1) | kh) ^ swz) << 3;                     \
            f16x8 a0 = *(const f16x8*)((Abuf) + (wm + ln31) * 64 + off);      \
            f16x8 a1 = *(const f16x8*)((Abuf) + (wm + 32 + ln31) * 64 + off); \
            f16x8 b  = *(const f16x8*)((Bbuf) + (wn + ln31) * 64 + off);      \
            acc0 = __builtin_amdgcn_mfma_f32_32x32x16_f16(a0, b, acc0, 0, 0, 0); \
            acc1 = __builtin_amdgcn_mfma_f32_32x32x16_f16(a1, b, acc1, 0, 0, 0); \
        }                                                                     \
    } while (0)

#define GEMM_PREAMBLE                                                         \
    const int t    = threadIdx.x;                                             \
    const int row  = t >> 3;                                                  \
    const int slot = t & 7;                                                   \
    const int kg   = (slot ^ (row & 7)) << 3;                                 \
    const f16* Ap = A  + (size_t)(m0 + row) * ldA + kg;                       \
    const f16* Bp = Bt + (size_t)(n0 + row) * ldB + kg;                       \
    const int o8 = t * 8;                                                     \
    const int lane = t & 63, w = t >> 6;                                      \
    const int wm = (w >> 1) * 64, wn = (w & 1) * 32;                          \
    const int ln31 = lane & 31, kh = lane >> 5;                               \
    const int swz = ln31 & 7;                                                 \
    f32x16 acc0 = {}, acc1 = {};                                              \
    STAGE(As0, Bs0);                                                          \
    for (int kb = 0; kb < Kt; kb += 2) {                                      \
        __syncthreads();                                                      \
        STAGE(As1, Bs1);                                                      \
        COMPUTE(As0, Bs0);                                                    \
        __syncthreads();                                                      \
        if (kb + 2 < Kt) STAGE(As0, Bs0);                                     \
        COMPUTE(As1, Bs1);                                                    \
    }

// 32x32 C/D mapping: col = lane&31, row = (reg&3) + 8*(reg>>2) + 4*(lane>>5)
// Variadic: braces do NOT protect commas in macro args; __VA_ARGS__ rejoins.
#define EPILOOP(...)                                                          \
    _Pragma("unroll")                                                         \
    for (int ib = 0; ib < 2; ++ib) {                                          \
        _Pragma("unroll")                                                     \
        for (int r = 0; r < 16; ++r) {                                        \
            const int ml   = wm + ib * 32 + (r & 3) + 8 * (r >> 2) + 4 * kh;  \
            const int ncol = n0 + wn + ln31;                                  \
            const float val = ib ? acc1[r] : acc0[r];                         \
            __VA_ARGS__                                                       \
        }                                                                     \
    }

// ---------------------------------------------------------------------------
// Generic GEMM for stages A, D, E.
// ---------------------------------------------------------------------------
template<int EPI>
__global__ __launch_bounds__(256)
void gemm128x64(const f16* __restrict__ A, const f16* __restrict__ Bt,
                f16* __restrict__ Ch, float* __restrict__ Cf,
                const float* __restrict__ bias,
                int Kt, int ldA, int ldB, size_t sA, size_t sB) {
    __shared__ __align__(16) f16 As0[128 * 64];   // 16 KB
    __shared__ __align__(16) f16 As1[128 * 64];   // 16 KB
    __shared__ __align__(16) f16 Bs0[64 * 64];    // 8 KB
    __shared__ __align__(16) f16 Bs1[64 * 64];    // 8 KB

    const int z  = blockIdx.z;
    const int m0 = blockIdx.x * 128;
    const int n0 = blockIdx.y * 64;
    A  += (size_t)z * sA;
    Bt += (size_t)z * sB;

    GEMM_PREAMBLE

    EPILOOP(
        const int mm = m0 + ml;
        if constexpr (EPI == 0) {          // stage A -> T1 rows u*16+bc
            int u = mm & 255;
            int slotc = (mm < 256) ? ncol : 256 + ncol;
            Ch[((size_t)(u * 16 + z)) * 512 + slotc] = (f16)val;
        } else if constexpr (EPI == 2) {   // stage D -> T2t [bo*256+x][512]
            int bo = mm >> 8;
            int u = mm & 255;
            int x     = (ncol < 256) ? ncol : ncol - 256;
            int slotc = (ncol < 256) ? u : 256 + u;
            Ch[((size_t)((bo << 8) + x)) * 512 + slotc] = (f16)val;
        } else {                            // stage E -> out fp32
            int bo = ncol >> 8;
            int x = ncol & 255;
            Cf[((size_t)bo * 256 + mm) * 256 + x] = val + bias[bo & 7];
        }
    )
}

// ---------------------------------------------------------------------------
// Stage B + Hermitian channel mix fused (iFFT scale g_u/N^2 folded here).
// ---------------------------------------------------------------------------
#define LSTR 68   // epilogue LDS row stride (f16)
__global__ __launch_bounds__(256)
void gemmB_fused(const f16* __restrict__ A, const f16* __restrict__ Bt,
                 const float2* __restrict__ W, f16* __restrict__ feats) {
    __shared__ __align__(16) f16 As0[128 * 64];
    __shared__ __align__(16) f16 As1[128 * 64];
    __shared__ __align__(16) f16 Bs0[64 * 64];
    __shared__ __align__(16) f16 Bs1[64 * 64];

    const int m0 = blockIdx.x * 128;      // u0 = blockIdx.x*8
    const int n0 = blockIdx.y * 64;       // v0 = blockIdx.y*32
    const int Kt = 8, ldA = 512, ldB = 512;

    GEMM_PREAMBLE

    // acc -> LDS F tile (overlay on As0/As1: 128*68*2 = 17.4 KB < 32 KB)
    f16* Ls = As0;
    __syncthreads();
    EPILOOP(
        const int nl = ncol - n0;         // local col (wn + ln31)
        Ls[ml * LSTR + nl] = (f16)val;
    )
    __syncthreads();

    // Hermitian channel mix: one thread per (u,v) in tile
    const int du = t >> 5, dv = t & 31;
    const int u = (m0 >> 4) + du;
    const int v = (n0 >> 1) + dv;
    const int u2 = (u == 0) ? 0 : NN - u;
    const int v2 = (v == 0) ? 0 : NN - v;
    const float gu = (u == 0) ? INV_NN2 : 2.f * INV_NN2;

    float fr[16], fi[16];
    #pragma unroll
    for (int bc = 0; bc < 16; ++bc) {
        f16x2 p = *(const f16x2*)&Ls[(du * 16 + bc) * LSTR + dv * 2];
        fr[bc] = (float)p.x;
        fi[bc] = (float)p.y;
    }

    #pragma unroll
    for (int o = 0; o < COUTC; ++o) {
        float whr[CINC], whi[CINC];
        #pragma unroll
        for (int c = 0; c < CINC; ++c) {
            size_t base = (size_t)(o * CINC + c) * NN;
            float2 w1 = W[(base + u)  * NN + v];
            float2 w2 = W[(base + u2) * NN + v2];
            whr[c] = 0.5f * (w1.x + w2.x);
            whi[c] = 0.5f * (w1.y - w2.y);
        }
        #pragma unroll
        for (int b = 0; b < BB; ++b) {
            float hr = 0.f, hi = 0.f;
            #pragma unroll
            for (int c = 0; c < CINC; ++c) {
                hr += fr[b * 4 + c] * whr[c] - fi[b * 4 + c] * whi[c];
                hi += fr[b * 4 + c] * whi[c] + fi[b * 4 + c] * whr[c];
            }
            f16x2 outp; outp.x = (f16)(hr * gu); outp.y = (f16)(hi * gu);
            *(f16x2*)&feats[((size_t)((b * COUTC + o) * 256 + u)) * 1024 + v * 2] = outp;
        }
    }
}

// ---------------------------------------------------------------------------
// kernel_launch
// ---------------------------------------------------------------------------
extern "C" void kernel_launch(void* const* d_in, const int* in_sizes, int n_in,
                              void* d_out, int out_size, void* d_ws, size_t ws_size,
                              hipStream_t stream) {
    const float*  im   = (const float*)d_in[0];
    const float2* W    = (const float2*)d_in[1];
    const float*  bias = (const float*)d_in[2];
    float*        out  = (float*)d_out;

    char* ws = (char*)d_ws;
    f16* Aa    = (f16*)(ws);                    // 512*256    = 256 KB
    f16* Bb    = (f16*)(ws + 262144);           // 1024*512   = 1 MB
    f16* Bd    = (f16*)(ws + 1310720);          // 512*1024   = 1 MB
    f16* Ae    = (f16*)(ws + 2359296);          // 256*512    = 256 KB
    f16* imT   = (f16*)(ws + 2621440);          // 16*256*256 = 2 MB
    f16* T1    = (f16*)(ws + 4718592);          // 4096*512   = 4 MB
    f16* feats = (f16*)(ws + 8912896);          // 8192*1024  = 16 MB
    f16* T2t   = (f16*)(ws + 25690112);         // 8192*512   = 8 MB (end 33.7 MB)

    // fused preps (2,359,296 elements)
    prep_all<<<9216, 256, 0, stream>>>(im, Aa, Bb, Bd, Ae, imT);

    // Stage A: per bc: [512 x 256] = Aa_h x imT[bc] -> T1 rows u*16+bc
    gemm128x64<0><<<dim3(4, 4, 16), 256, 0, stream>>>(Aa, imT, T1, nullptr, nullptr,
                                                      4, 256, 256, 0, 65536);
    // Stage B + mix: [4096 x 1024] GEMM -> in-LDS F -> Hermitian mix -> feats
    gemmB_fused<<<dim3(32, 16), 256, 0, stream>>>(T1, Bb, W, feats);

    // Stage D: [8192 x 512] = feats x Bd -> T2t (scale folded in feats)
    gemm128x64<2><<<dim3(64, 8, 1), 256, 0, stream>>>(feats, Bd, T2t, nullptr, nullptr,
                                                      16, 1024, 1024, 0, 0);
    // Stage E: [256 x 8192] = Ae_h x T2t + bias -> out
    gemm128x64<3><<<dim3(2, 128, 1), 256, 0, stream>>>(Ae, T2t, nullptr, out, bias,
                                                       8, 512, 512, 0, 0);
}